// Round 10
// baseline (281.458 us; speedup 1.0000x reference)
//
#include <hip/hip_runtime.h>
#include <hip/hip_bf16.h>

// ---------------------------------------------------------------------------
// Task1_bf_final_CSW2D round 20 (base = R19, 259.4us verified):
//  conv23 PAIR-PACKED MFMA (conv1's R11 trick applied to K=15):
//   A rows 0..7 = tile T taps (4m'+kq), rows 8..15 = tile T+1 taps
//   (4m'+kq-16); 8 MFMA + 8 ds_read per tile PAIR.  Same MFMA/ds_read
//   count, but the epilogue is FULL-WAVE and HALVED (44 vs 88 wave-instrs
//   per pixel: R19 counters showed VALUBusy 33% = top pipe, with half-wave
//   idle in the lane<32 epilogue).  Outputs bit-identical (zero-A MFMA adds
//   exact +0; per-output accumulation order unchanged).  Epilogue reduce =
//   conv1's proven shfl_xor(32) + lane0/lane16 pattern.
// Everything else identical to R19.
// ---------------------------------------------------------------------------

#define E_    128
#define NPIX  32768
#define NS_   (NPIX * E_)
#define NSAMP 2048

static constexpr double PI_D     = 3.14159265358979323846;
static constexpr double FS_D     = 20832000.0;
static constexpr double FDEMOD_D = 5208000.0;
static constexpr double C_D      = 1540.0;

typedef __attribute__((ext_vector_type(8))) short short8;
typedef __attribute__((ext_vector_type(4))) float f32x4;

union U8 { uint4 u4; unsigned u32[4]; unsigned short us[8]; short8 s8; };

__device__ __forceinline__ unsigned short f2bf(float f) {
  unsigned u = __float_as_uint(f);
  unsigned r = (u + 0x7fffu + ((u >> 16) & 1u)) >> 16;
  return (unsigned short)r;
}
// packed f32x2 -> bf16x2 (lo in low half), RNE — one VALU instruction
__device__ __forceinline__ unsigned cvt_pk_bf16(float lo, float hi) {
  unsigned r;
  asm("v_cvt_pk_bf16_f32 %0, %1, %2" : "=v"(r) : "v"(lo), "v"(hi));
  return r;
}
__device__ __forceinline__ float bflo(unsigned w) { return __uint_as_float(w << 16); }
__device__ __forceinline__ float bfhi(unsigned w) { return __uint_as_float(w & 0xFFFF0000u); }
__device__ __forceinline__ float bf2f(unsigned short s) {
  return __uint_as_float((unsigned)s << 16);
}

__device__ __forceinline__ float wave_reduce_sum(float v) {
  #pragma unroll
  for (int off = 32; off; off >>= 1) v += __shfl_xor(v, off);
  return v;
}
__device__ __forceinline__ float wave_reduce_max(float v) {
  #pragma unroll
  for (int off = 32; off; off >>= 1) v = fmaxf(v, __shfl_xor(v, off));
  return v;
}

// ---------------------------------------------------------------------------
// Folded BN-stats, vectorized + fully unrolled (R15-proven).
// partial = [NBLK][16] f32 (cols 0..7 sums, 8..15 ssqs) read as float4.
// ---------------------------------------------------------------------------
template <int NBLK>
__device__ __forceinline__ void stats8v(const float4* __restrict__ part4,
                                        const float* __restrict__ g,
                                        const float* __restrict__ beta,
                                        float* __restrict__ A,
                                        float* __restrict__ Bc) {
  __shared__ float red[4][16];
  __shared__ float sums[16];
  const int tid = threadIdx.x;
  constexpr int K = (NBLK * 4) / 256;
  float ax = 0.f, ay = 0.f, az = 0.f, aw = 0.f;
  #pragma unroll
  for (int k = 0; k < K; ++k) {
    const float4 q = part4[tid + k * 256];
    ax += q.x; ay += q.y; az += q.z; aw += q.w;
  }
  #pragma unroll
  for (int off = 4; off <= 32; off <<= 1) {
    ax += __shfl_xor(ax, off);
    ay += __shfl_xor(ay, off);
    az += __shfl_xor(az, off);
    aw += __shfl_xor(aw, off);
  }
  const int lane = tid & 63, wv = tid >> 6;
  if (lane < 4) {
    red[wv][lane * 4 + 0] = ax;
    red[wv][lane * 4 + 1] = ay;
    red[wv][lane * 4 + 2] = az;
    red[wv][lane * 4 + 3] = aw;
  }
  __syncthreads();
  if (tid < 16)
    sums[tid] = red[0][tid] + red[1][tid] + red[2][tid] + red[3][tid];
  __syncthreads();
  if (tid < 8) {
    const float s = sums[tid], ss = sums[tid + 8];
    const float count = (float)NS_;
    const float mu = s / count;
    const float var = fmaxf(ss / count - mu * mu, 0.f);
    const float Av = g[tid] * rsqrtf(var + 1e-5f);
    red[0][tid] = Av;
    red[1][tid] = beta[tid] - mu * Av;
  }
  __syncthreads();
  #pragma unroll
  for (int i = 0; i < 8; ++i) { A[i] = red[0][i]; Bc[i] = red[1][i]; }
}

// BN+relu one 16B unit (8 channels of one e), repack to bf16 via cvt_pk
__device__ __forceinline__ uint4 bn_unit(uint4 v, const float* A, const float* B) {
  U8 in; in.u4 = v;
  unsigned ow[4];
  #pragma unroll
  for (int w = 0; w < 4; ++w) {
    const unsigned wd = in.u32[w];
    const float yl = fmaxf(0.f, fmaf(A[2 * w], bflo(wd), B[2 * w]));
    const float yh = fmaxf(0.f, fmaf(A[2 * w + 1], bfhi(wd), B[2 * w + 1]));
    ow[w] = cvt_pk_bf16(yl, yh);
  }
  return make_uint4(ow[0], ow[1], ow[2], ow[3]);
}

// ---------------------------------------------------------------------------
// init: PER-BLOCK max of i^2+q^2 (float4, no atomics).
// ---------------------------------------------------------------------------
__global__ __launch_bounds__(256) void k_init(const float4* __restrict__ id4,
                                              const float4* __restrict__ qd4,
                                              float* __restrict__ pmaxsq) {
  const int idx = blockIdx.x * 256 + threadIdx.x;
  const float4 iv = id4[idx];
  const float4 qv = qd4[idx];
  float m = fmaxf(fmaxf(iv.x * iv.x + qv.x * qv.x, iv.y * iv.y + qv.y * qv.y),
                  fmaxf(iv.z * iv.z + qv.z * qv.z, iv.w * iv.w + qv.w * qv.w));
  m = wave_reduce_max(m);
  __shared__ float sm[4];
  if ((threadIdx.x & 63) == 0) sm[threadIdx.x >> 6] = m;
  __syncthreads();
  if (threadIdx.x == 0)
    pmaxsq[blockIdx.x] = fmaxf(fmaxf(sm[0], sm[1]), fmaxf(sm[2], sm[3]));
}

// ---------------------------------------------------------------------------
// beamform, e-major output x0t[e][p]: coalesced 4B/lane stores.
// ---------------------------------------------------------------------------
__global__ __launch_bounds__(256) void k_beamform(
    const float4* __restrict__ id4, const float4* __restrict__ qd4,
    const float* __restrict__ angles, const float* __restrict__ ele_pos,
    const float* __restrict__ time_zero, const float* __restrict__ grid,
    const float4* __restrict__ pmaxsq4, unsigned* __restrict__ x0t) {
  __shared__ float2 sig[NSAMP];          // 16 KB
  __shared__ float smax[4];
  const int e = blockIdx.x & 127;
  const int chunk = blockIdx.x >> 7;     // 0..31

  const float4* irow = id4 + e * (NSAMP / 4);
  const float4* qrow = qd4 + e * (NSAMP / 4);
  #pragma unroll
  for (int k0 = 0; k0 < 2; ++k0) {
    const int k = k0 * 256 + threadIdx.x;
    const float4 iv = irow[k];
    const float4 qv = qrow[k];
    sig[4 * k + 0] = make_float2(iv.x, qv.x);
    sig[4 * k + 1] = make_float2(iv.y, qv.y);
    sig[4 * k + 2] = make_float2(iv.z, qv.z);
    sig[4 * k + 3] = make_float2(iv.w, qv.w);
  }
  // self-reduce the normalization max (16 KB, L2-hot; float4, unrolled)
  float mx = 0.f;
  #pragma unroll
  for (int k = 0; k < 4; ++k) {
    const float4 q = pmaxsq4[threadIdx.x + k * 256];
    mx = fmaxf(mx, fmaxf(fmaxf(q.x, q.y), fmaxf(q.z, q.w)));
  }
  mx = wave_reduce_max(mx);
  if ((threadIdx.x & 63) == 0) smax[threadIdx.x >> 6] = mx;
  __syncthreads();
  const float inv =
      1.0f / sqrtf(fmaxf(fmaxf(smax[0], smax[1]), fmaxf(smax[2], smax[3])));

  const float ang = angles[0];
  const float tz  = time_zero[0];

  constexpr float SC    = (float)(FS_D / C_D);
  constexpr float TH2R  = (float)(2.0 * FDEMOD_D / C_D);
  constexpr float TWOPI = (float)(2.0 * PI_D);

  const float sa = __sinf(ang);
  const float ca = __cosf(ang);
  const float ta = sa / ca;
  const float ex  = ele_pos[e * 3];
  const float ex0 = ele_pos[0];
  const float exl = ele_pos[127 * 3];

  #pragma unroll
  for (int s = 0; s < 4; ++s) {
    const int p = chunk * 1024 + s * 256 + threadIdx.x;
    const float px = grid[p * 3 + 0];
    const float pz = grid[p * 3 + 2];

    const float txdel = (px * sa + pz * ca + tz * (float)C_D) * SC;
    const float dx = px - ex;
    const float rxdel = sqrtf(dx * dx + pz * pz) * SC;

    const float delays = txdel + rxdel;
    const float d0 = floorf(delays);
    const float frac = delays - d0;
    const int i0 = (int)d0;

    const int c0 = min(max(i0, 0), NSAMP - 1);
    const int c1 = min(max(i0 + 1, 0), NSAMP - 1);
    const float2 s0 = sig[c0];
    const float2 s1 = sig[c1];
    const bool m0 = (i0 >= 0) && (i0 < NSAMP);
    const bool m1 = (i0 + 1 >= 0) && (i0 + 1 < NSAMP);
    const float iv0 = m0 ? s0.x : 0.f;
    const float qv0 = m0 ? s0.y : 0.f;
    const float iv1 = m1 ? s1.x : 0.f;
    const float qv1 = m1 ? s1.y : 0.f;
    const float ifoc = (iv0 * (1.f - frac) + iv1 * frac) * inv;
    const float qfoc = (qv0 * (1.f - frac) + qv1 * frac) * inv;

    // theta/2pi = delays*0.25 - pz*TH2R  (exact: FS = 4*FDEMOD)
    const float trev = fmaf(delays, 0.25f, -pz * TH2R);
    const float fr = trev - floorf(trev);
    const float st = __sinf(fr * TWOPI);
    const float ct = __cosf(fr * TWOPI);
    const float ir = ifoc * ct - qfoc * st;
    const float qr = qfoc * ct + ifoc * st;

    const float avx = fabsf(dx);
    const bool mrx = (fabsf(pz) > avx) || (avx <= 0.001f) ||
                     ((dx >= 0.001f) && (px <= ex0)) ||
                     ((dx <= -0.001f) && (px >= exl));
    const float xproj = px - pz * ta;
    const bool mtx = (xproj >= ex0 * 1.2f) && (xproj <= exl * 1.2f);
    const float a = (mrx && mtx) ? 1.f : 0.f;

    x0t[(size_t)e * NPIX + p] = cvt_pk_bf16(ir * a, qr * a);
  }
}

// ---------------------------------------------------------------------------
// conv1: IC=2, K=65, pad=32, OC=8.  Block-tiled LDS staging, PAIR-PACKED
// MFMA (rows 0..7 tile t, rows 8..15 tile t+1): 24 MFMA/px, full-wave
// epilogue.  Output: compact [p][128][8ch].
// ---------------------------------------------------------------------------
#define CONV1_P 32
#define ROWW    213

__global__ __launch_bounds__(256, 4) void k_conv1(
    const unsigned* __restrict__ x0t, const float* __restrict__ wgt,
    const float* __restrict__ bias, uint2* __restrict__ outp,
    float* __restrict__ partial,
    float* __restrict__ sumI, float* __restrict__ sumQ) {
  __shared__ unsigned tile[CONV1_P * ROWW];   // 27,264 B
  const int tid = threadIdx.x;
  const int lane = tid & 63;
  const int wv = tid >> 6;
  const int n = lane & 15, kq = lane >> 4;
  const int p0 = blockIdx.x * CONV1_P;

  // Pair-packed weight fragments: rows n<8 use window m (tile t); rows
  // n in 8..15 use window m-1 (tile t+1).  m=5/lower and m=0/upper are zero.
  short8 af2[6];
  #pragma unroll
  for (int m = 0; m < 6; ++m) {
    U8 u;
    #pragma unroll
    for (int j = 0; j < 8; ++j) {
      const int oc = n & 7;
      const int mm = (n < 8) ? m : (m - 1);
      const int tap = mm * 16 + kq * 4 + (j >> 1);
      const int ic = j & 1;
      const float w = (mm >= 0 && tap < 65) ? wgt[(oc * 2 + ic) * 65 + tap] : 0.f;
      u.us[j] = f2bf(w);
    }
    af2[m] = u.s8;
  }
  float bias_r[4];
  #pragma unroll
  for (int r = 0; r < 4; ++r) bias_r[r] = bias[(kq & 1) * 4 + r];

  // ---- stage tile: zero halos, transpose-load data [e][p] -> [p][32+e] ----
  for (int i = tid; i < CONV1_P * 32; i += 256)
    tile[(i >> 5) * ROWW + (i & 31)] = 0u;               // words [0,32)
  for (int i = tid; i < CONV1_P * 64; i += 256) {
    const int c = i & 63;
    if (c < ROWW - 160) tile[(i >> 6) * ROWW + 160 + c] = 0u;  // words [160,213)
  }
  {
    const int lp = tid & 31;
    const int e0 = tid >> 5;                              // 0..7
    #pragma unroll
    for (int i = 0; i < 16; ++i) {
      const int e = i * 8 + e0;
      tile[lp * ROWW + 32 + e] = x0t[(size_t)e * NPIX + p0 + lp];
    }
  }
  __syncthreads();

  float sum[4] = {0, 0, 0, 0}, ssq[4] = {0, 0, 0, 0};
  const int sbase = n + kq * 4;

  for (int j8 = 0; j8 < 8; ++j8) {
    const int lpx = wv * 8 + j8;
    const int p = p0 + lpx;
    const unsigned* row = tile + lpx * ROWW;
    uint2* orow = outp + (size_t)p * 256;

    // e-sums for k_final (bf16 inputs, same order as R10)
    {
      const unsigned v0 = row[32 + lane];
      const unsigned v1 = row[96 + lane];
      float si = bflo(v0) + bflo(v1);
      float sq = bfhi(v0) + bfhi(v1);
      si = wave_reduce_sum(si);
      sq = wave_reduce_sum(sq);
      if (lane == 0) { sumI[p] = si; sumQ[p] = sq; }
    }

    U8 win[12];
    #pragma unroll
    for (int q = 0; q < 12; ++q)
      #pragma unroll
      for (int c = 0; c < 4; ++c) win[q].u32[c] = row[sbase + 16 * q + c];

    #pragma unroll
    for (int pi = 0; pi < 4; ++pi) {
      f32x4 acc = {bias_r[0], bias_r[1], bias_r[2], bias_r[3]};
      #pragma unroll
      for (int m = 0; m < 6; ++m)
        acc = __builtin_amdgcn_mfma_f32_16x16x32_bf16(af2[m], win[2 * pi + m].s8,
                                                      acc, 0, 0, 0);
      // rows kq*4+r: kq<2 -> tile 2pi (oc=(kq&1)*4+r), kq>=2 -> tile 2pi+1
      const unsigned lo = cvt_pk_bf16(acc[0], acc[1]);
      const unsigned hi = cvt_pk_bf16(acc[2], acc[3]);
      orow[((2 * pi + (kq >> 1)) * 16 + n) * 2 + (kq & 1)] = make_uint2(lo, hi);
      #pragma unroll
      for (int r = 0; r < 4; ++r) { const float v = acc[r]; sum[r] += v; ssq[r] += v * v; }
    }
  }

  // reduce over n (offs 1..8), then combine kq<->kq+2 (off 32)
  #pragma unroll
  for (int off = 1; off <= 8; off <<= 1)
    #pragma unroll
    for (int r = 0; r < 4; ++r) { sum[r] += __shfl_xor(sum[r], off); ssq[r] += __shfl_xor(ssq[r], off); }
  #pragma unroll
  for (int r = 0; r < 4; ++r) { sum[r] += __shfl_xor(sum[r], 32); ssq[r] += __shfl_xor(ssq[r], 32); }
  __shared__ float s_red[4][16];
  if (lane == 0)
    #pragma unroll
    for (int r = 0; r < 4; ++r) { s_red[wv][r] = sum[r]; s_red[wv][8 + r] = ssq[r]; }
  if (lane == 16)
    #pragma unroll
    for (int r = 0; r < 4; ++r) { s_red[wv][4 + r] = sum[r]; s_red[wv][12 + r] = ssq[r]; }
  __syncthreads();
  if (tid < 16)
    partial[blockIdx.x * 16 + tid] =
        s_red[0][tid] + s_red[1][tid] + s_red[2][tid] + s_red[3][tid];
}

// ---------------------------------------------------------------------------
// conv2/3: IC=8, K=15, pad=7, OC=8.  Per-wave PRIVATE LDS row staging (no
// intra-loop barriers).  Input BN finalized in-kernel from predecessor's
// partial (stats8v<NBLK>, unrolled); BN+relu once per element; halos zeroed.
// PAIR-PACKED MFMA: A rows 0..7 = tile T (taps 4m+kq), rows 8..15 = tile
// T+1 (taps 4m+kq-16); 8 MFMA + 8 ds_read per tile pair, FULL-WAVE epilogue
// (C rows: kq<2 -> tile T ch (kq&1)*4+r, kq>=2 -> tile T+1).
// ---------------------------------------------------------------------------
template <int NBLK_IN>
__global__ __launch_bounds__(256) void k_conv23(
    const uint4* __restrict__ inp, const float* __restrict__ wgt,
    const float* __restrict__ bias,
    const float4* __restrict__ part_in,
    const float* __restrict__ g_in, const float* __restrict__ be_in,
    uint2* __restrict__ outp, float* __restrict__ partial) {
  __shared__ uint4 s_row[4][144];
  const int tid = threadIdx.x;
  const int lane = tid & 63;
  const int wv = tid >> 6;
  const int gw = blockIdx.x * 4 + wv;
  const int n = lane & 15, kq = lane >> 4;

  // prologue load for first pixel (in flight across the stats fold)
  uint4 v0 = inp[(size_t)gw * 128 + lane];
  uint4 v1 = inp[(size_t)gw * 128 + 64 + lane];

  float A[8], Bc[8];
  stats8v<NBLK_IN>(part_in, g_in, be_in, A, Bc);

  // Pair-packed weight fragments: rows n<8 = tile T taps 4m+kq (<15),
  // rows 8..15 = tile T+1 taps 4m+kq-16 (>=0).
  short8 af2[8];
  #pragma unroll
  for (int m = 0; m < 8; ++m) {
    U8 u;
    #pragma unroll
    for (int j = 0; j < 8; ++j) {
      const int oc = n & 7;
      const int tap = (n < 8) ? (m * 4 + kq) : (m * 4 + kq - 16);
      const float w = (tap >= 0 && tap < 15) ? wgt[(oc * 8 + j) * 15 + tap] : 0.f;
      u.us[j] = f2bf(w);
    }
    af2[m] = u.s8;
  }
  float bias_r[4];
  #pragma unroll
  for (int r = 0; r < 4; ++r) bias_r[r] = bias[(kq & 1) * 4 + r];

  uint4* lds = s_row[wv];
  if (lane < 7)  lds[lane] = make_uint4(0, 0, 0, 0);
  if (lane >= 7 && lane < 16) lds[128 + lane] = make_uint4(0, 0, 0, 0);

  float sum[4] = {0, 0, 0, 0}, ssq[4] = {0, 0, 0, 0};

  #pragma unroll 1
  for (int it = 0; it < 4; ++it) {
    const int p = gw + it * 8192;
    lds[7 + lane]  = bn_unit(v0, A, Bc);
    lds[71 + lane] = bn_unit(v1, A, Bc);

    // prefetch next pixel (latency hides under the tile-pair loop)
    if (it < 3) {
      const uint4* ng = inp + (size_t)(p + 8192) * 128;
      v0 = ng[lane];
      v1 = ng[64 + lane];
    }

    uint2* orow = outp + (size_t)p * 256;
    #pragma unroll
    for (int P = 0; P < 4; ++P) {
      const int base = P * 32 + n + kq;
      U8 b[8];
      #pragma unroll
      for (int m = 0; m < 8; ++m) b[m].u4 = lds[base + m * 4];
      f32x4 acc = {bias_r[0], bias_r[1], bias_r[2], bias_r[3]};
      #pragma unroll
      for (int m = 0; m < 8; ++m)
        acc = __builtin_amdgcn_mfma_f32_16x16x32_bf16(af2[m], b[m].s8, acc, 0, 0, 0);
      // rows kq*4+r: kq<2 -> tile 2P, kq>=2 -> tile 2P+1; ch (kq&1)*4+r
      const unsigned lo = cvt_pk_bf16(acc[0], acc[1]);
      const unsigned hi = cvt_pk_bf16(acc[2], acc[3]);
      orow[((P * 2 + (kq >> 1)) * 16 + n) * 2 + (kq & 1)] = make_uint2(lo, hi);
      #pragma unroll
      for (int r = 0; r < 4; ++r) { const float v = acc[r]; sum[r] += v; ssq[r] += v * v; }
    }
  }

  // reduce over n (offs 1..8), then combine kq<->kq+2 (off 32)
  #pragma unroll
  for (int off = 1; off <= 8; off <<= 1)
    #pragma unroll
    for (int r = 0; r < 4; ++r) { sum[r] += __shfl_xor(sum[r], off); ssq[r] += __shfl_xor(ssq[r], off); }
  #pragma unroll
  for (int r = 0; r < 4; ++r) { sum[r] += __shfl_xor(sum[r], 32); ssq[r] += __shfl_xor(ssq[r], 32); }
  __shared__ float s_red[4][16];
  if (lane == 0)
    #pragma unroll
    for (int r = 0; r < 4; ++r) { s_red[wv][r] = sum[r]; s_red[wv][8 + r] = ssq[r]; }
  if (lane == 16)
    #pragma unroll
    for (int r = 0; r < 4; ++r) { s_red[wv][4 + r] = sum[r]; s_red[wv][12 + r] = ssq[r]; }
  __syncthreads();
  if (tid < 16)
    partial[blockIdx.x * 16 + tid] =
        s_red[0][tid] + s_red[1][tid] + s_red[2][tid] + s_red[3][tid];
}

// ---------------------------------------------------------------------------
// conv4: IC=8, K=3, pad=1, OC=1.  VALU; BN3+relu fused on load (BN3 finalized
// in-kernel via stats8v<2048>); 2048 blocks x 8 outputs/thread.  Output bf16.
// ---------------------------------------------------------------------------
__global__ __launch_bounds__(256) void k_conv4(
    const uint4* __restrict__ inp,
    const float4* __restrict__ part_in,
    const float* __restrict__ g3, const float* __restrict__ be3,
    const float* __restrict__ w4, const float* __restrict__ b4,
    unsigned short* __restrict__ y4b, float* __restrict__ partial) {
  float A[8], Bc[8];
  stats8v<2048>(part_in, g3, be3, A, Bc);

  const float bb = b4[0];
  float w4r[24];
  #pragma unroll
  for (int i = 0; i < 24; ++i) w4r[i] = w4[i];

  float s = 0.f, ss = 0.f;
  #pragma unroll 1
  for (int it = 0; it < 8; ++it) {
    const int idx = blockIdx.x * 256 + threadIdx.x + it * 524288;
    const int p = idx >> 7, e = idx & 127;
    float acc = bb;
    const uint4* row = inp + (size_t)p * 128 + e;
    #pragma unroll
    for (int kt = 0; kt < 3; ++kt) {
      const int ee = e + kt - 1;
      if (ee >= 0 && ee < E_) {
        U8 u; u.u4 = row[kt - 1];
        #pragma unroll
        for (int i = 0; i < 8; ++i) {
          const unsigned wd = u.u32[i >> 1];
          const float x = (i & 1) ? bfhi(wd) : bflo(wd);
          const float v = fmaxf(0.f, fmaf(A[i], x, Bc[i]));
          acc = fmaf(w4r[i * 3 + kt], v, acc);
        }
      }
    }
    y4b[idx] = f2bf(acc);
    s += acc;
    ss += acc * acc;
  }

  s = wave_reduce_sum(s);
  ss = wave_reduce_sum(ss);
  __shared__ float sm[4][2];
  if ((threadIdx.x & 63) == 0) { sm[threadIdx.x >> 6][0] = s; sm[threadIdx.x >> 6][1] = ss; }
  __syncthreads();
  if (threadIdx.x == 0) {
    partial[blockIdx.x * 2 + 0] = sm[0][0] + sm[1][0] + sm[2][0] + sm[3][0];
    partial[blockIdx.x * 2 + 1] = sm[0][1] + sm[1][1] + sm[2][1] + sm[3][1];
  }
}

// ---------------------------------------------------------------------------
// final: BN4 finalized in-kernel from conv4's 16KB partial (vectorized,
// unrolled fold); singleW = sum_e relu(A4*y4+B4); comp = singleW*(sum_e x)/E;
// dB.  Per-block max.
// ---------------------------------------------------------------------------
__global__ __launch_bounds__(256) void k_final(const float* __restrict__ sumI,
                                               const float* __restrict__ sumQ,
                                               const unsigned short* __restrict__ y4b,
                                               const float4* __restrict__ part_in,
                                               const float* __restrict__ g4,
                                               const float* __restrict__ be4,
                                               float* __restrict__ ydb,
                                               float* __restrict__ pmax) {
  __shared__ float sAB[2];
  {
    const int tid = threadIdx.x;
    // part_in = 2048 float2 pairs = 1024 float4; 4 unrolled loads/thread
    float s = 0.f, ss = 0.f;
    #pragma unroll
    for (int k = 0; k < 4; ++k) {
      const float4 q = part_in[tid + k * 256];
      s += q.x + q.z;
      ss += q.y + q.w;
    }
    s = wave_reduce_sum(s);
    ss = wave_reduce_sum(ss);
    __shared__ float sm[4][2];
    if ((tid & 63) == 0) { sm[tid >> 6][0] = s; sm[tid >> 6][1] = ss; }
    __syncthreads();
    if (tid == 0) {
      s  = sm[0][0] + sm[1][0] + sm[2][0] + sm[3][0];
      ss = sm[0][1] + sm[1][1] + sm[2][1] + sm[3][1];
      const float count = (float)NS_;
      const float mu = s / count;
      const float var = fmaxf(ss / count - mu * mu, 0.f);
      const float Av = g4[0] * rsqrtf(var + 1e-5f);
      sAB[0] = Av;
      sAB[1] = be4[0] - mu * Av;
    }
    __syncthreads();
  }
  const float A = sAB[0], B = sAB[1];

  const int w = threadIdx.x >> 6;
  const int lane = threadIdx.x & 63;
  const int p = blockIdx.x * 4 + w;
  const size_t base = (size_t)p * E_;

  float sw = fmaxf(0.f, fmaf(A, bf2f(y4b[base + lane]), B)) +
             fmaxf(0.f, fmaf(A, bf2f(y4b[base + lane + 64]), B));
  sw = wave_reduce_sum(sw);

  __shared__ float s_m[4];
  if (lane == 0) {
    const float ci = sw * sumI[p] * (1.f / (float)E_);
    const float cq = sw * sumQ[p] * (1.f / (float)E_);
    const float mag = sqrtf(ci * ci + cq * cq);
    const float v = 20.f * log10f(mag + 1e-20f);
    ydb[p] = v;
    s_m[w] = v;
  }
  __syncthreads();
  if (threadIdx.x == 0)
    pmax[blockIdx.x] = fmaxf(fmaxf(s_m[0], s_m[1]), fmaxf(s_m[2], s_m[3]));
}

// k_sub with inline global-max: each block re-reduces pmax[8192] (float4)
__global__ __launch_bounds__(256) void k_sub(const float* __restrict__ ydb,
                                             const float4* __restrict__ pmax4,
                                             float* __restrict__ out) {
  float m = -3.4e38f;
  #pragma unroll
  for (int k = 0; k < 8; ++k) {
    const float4 q = pmax4[threadIdx.x + k * 256];
    m = fmaxf(m, fmaxf(fmaxf(q.x, q.y), fmaxf(q.z, q.w)));
  }
  m = wave_reduce_max(m);
  __shared__ float sm[4];
  if ((threadIdx.x & 63) == 0) sm[threadIdx.x >> 6] = m;
  __syncthreads();
  __shared__ float sgm;
  if (threadIdx.x == 0)
    sgm = fmaxf(fmaxf(sm[0], sm[1]), fmaxf(sm[2], sm[3]));
  __syncthreads();
  const int i = blockIdx.x * 256 + threadIdx.x;
  out[i] = ydb[i] - sgm;
}

// ---------------------------------------------------------------------------
// Workspace layout (bytes).  Region A is time-multiplexed:
//   x0t (16.7MB) -> buf2 (67MB, dead after conv3) -> y4b (8.4MB) + ydb + pmax.
// partial is double-buffered: part0/part1 (128KB each).
// ---------------------------------------------------------------------------
static constexpr size_t OFF_A     = 0;            // 67,108,864 region
static constexpr size_t OFF_Y4    = 0;            // bf16 [NS]  (in A)
static constexpr size_t OFF_YDB   = 16777216;     // f32 [NPIX] (in A)
static constexpr size_t OFF_PMAX  = 16908288;     // f32 [8192] (in A)
static constexpr size_t OFF_BUF1  = 67108864;     // 67,108,864
static constexpr size_t OFF_SUMI  = 134217728;    // 131,072
static constexpr size_t OFF_SUMQ  = 134348800;    // 131,072
static constexpr size_t OFF_PART0 = 134479872;    // 131,072
static constexpr size_t OFF_PART1 = 134610944;    // 131,072
static constexpr size_t OFF_PMSQ  = 134742016;    // 16,384 (4096 f32)

extern "C" void kernel_launch(void* const* d_in, const int* in_sizes, int n_in,
                              void* d_out, int out_size, void* d_ws, size_t ws_size,
                              hipStream_t stream) {
  const float* idata     = (const float*)d_in[0];
  const float* qdata     = (const float*)d_in[1];
  const float* angles    = (const float*)d_in[2];
  const float* ele_pos   = (const float*)d_in[3];
  const float* time_zero = (const float*)d_in[4];
  const float* grid      = (const float*)d_in[5];
  const float* w1 = (const float*)d_in[6];  const float* b1 = (const float*)d_in[7];
  const float* g1 = (const float*)d_in[8];  const float* be1 = (const float*)d_in[9];
  const float* w2 = (const float*)d_in[10]; const float* b2 = (const float*)d_in[11];
  const float* g2 = (const float*)d_in[12]; const float* be2 = (const float*)d_in[13];
  const float* w3 = (const float*)d_in[14]; const float* b3 = (const float*)d_in[15];
  const float* g3 = (const float*)d_in[16]; const float* be3 = (const float*)d_in[17];
  const float* w4 = (const float*)d_in[18]; const float* b4 = (const float*)d_in[19];
  const float* g4 = (const float*)d_in[20]; const float* be4 = (const float*)d_in[21];

  char* ws = (char*)d_ws;
  unsigned*       x0t   = (unsigned*)(ws + OFF_A);       // [e][p] bf16-pairs
  uint4*          buf2  = (uint4*)(ws + OFF_A);          // [p][128] units
  unsigned short* y4b   = (unsigned short*)(ws + OFF_Y4);
  float*          ydb   = (float*)(ws + OFF_YDB);
  float*          pmax  = (float*)(ws + OFF_PMAX);
  uint4*          buf1  = (uint4*)(ws + OFF_BUF1);
  float*          sumI  = (float*)(ws + OFF_SUMI);
  float*          sumQ  = (float*)(ws + OFF_SUMQ);
  float*          part0 = (float*)(ws + OFF_PART0);
  float*          part1 = (float*)(ws + OFF_PART1);
  float*          pmsq  = (float*)(ws + OFF_PMSQ);

  k_init<<<4096, 256, 0, stream>>>((const float4*)idata, (const float4*)qdata, pmsq);
  k_beamform<<<4096, 256, 0, stream>>>((const float4*)idata, (const float4*)qdata,
                                       angles, ele_pos, time_zero, grid,
                                       (const float4*)pmsq, x0t);

  k_conv1<<<NPIX / CONV1_P, 256, 0, stream>>>(x0t, w1, b1, (uint2*)buf1, part0,
                                              sumI, sumQ);

  k_conv23<1024><<<2048, 256, 0, stream>>>(buf1, w2, b2, (const float4*)part0,
                                           g1, be1, (uint2*)buf2, part1);

  k_conv23<2048><<<2048, 256, 0, stream>>>(buf2, w3, b3, (const float4*)part1,
                                           g2, be2, (uint2*)buf1, part0);

  k_conv4<<<2048, 256, 0, stream>>>(buf1, (const float4*)part0, g3, be3,
                                    w4, b4, y4b, part1);

  k_final<<<NPIX / 4, 256, 0, stream>>>(sumI, sumQ, y4b, (const float4*)part1,
                                        g4, be4, ydb, pmax);
  k_sub<<<NPIX / 256, 256, 0, stream>>>(ydb, (const float4*)pmax, (float*)d_out);
}

// Round 11
// 253.746 us; speedup vs baseline: 1.1092x; 1.1092x over previous
//
#include <hip/hip_runtime.h>
#include <hip/hip_bf16.h>

// ---------------------------------------------------------------------------
// Task1_bf_final_CSW2D round 21 (base = R19, 259.4us verified):
//  - conv23 REVERTED to R19's 52-VGPR form (R20 pair-packing regressed
//    44.2->56.4us: +24 VGPR and an 8-deep MFMA chain hurt the latency-bound
//    kernel; third null/regression on conv23 interior -> leave it).
//  - Tail-kernel fold-traffic trim (mechanism: consumer-side stats folds pay
//    L2 bandwidth x #blocks):
//     conv4: 2048 -> 1024 blocks x 16 outputs (fold aggregate 256->128MB;
//            its partial shrinks to [1024][2] = 8KB).
//     k_final: 8192 -> 2048 blocks x 16 pixels (fold aggregate 131->16MB).
//     k_sub: reads 2048-entry pmax (512 float4).
// Everything else identical to R19.
// ---------------------------------------------------------------------------

#define E_    128
#define NPIX  32768
#define NS_   (NPIX * E_)
#define NSAMP 2048

static constexpr double PI_D     = 3.14159265358979323846;
static constexpr double FS_D     = 20832000.0;
static constexpr double FDEMOD_D = 5208000.0;
static constexpr double C_D      = 1540.0;

typedef __attribute__((ext_vector_type(8))) short short8;
typedef __attribute__((ext_vector_type(4))) float f32x4;

union U8 { uint4 u4; unsigned u32[4]; unsigned short us[8]; short8 s8; };

__device__ __forceinline__ unsigned short f2bf(float f) {
  unsigned u = __float_as_uint(f);
  unsigned r = (u + 0x7fffu + ((u >> 16) & 1u)) >> 16;
  return (unsigned short)r;
}
// packed f32x2 -> bf16x2 (lo in low half), RNE — one VALU instruction
__device__ __forceinline__ unsigned cvt_pk_bf16(float lo, float hi) {
  unsigned r;
  asm("v_cvt_pk_bf16_f32 %0, %1, %2" : "=v"(r) : "v"(lo), "v"(hi));
  return r;
}
__device__ __forceinline__ float bflo(unsigned w) { return __uint_as_float(w << 16); }
__device__ __forceinline__ float bfhi(unsigned w) { return __uint_as_float(w & 0xFFFF0000u); }
__device__ __forceinline__ float bf2f(unsigned short s) {
  return __uint_as_float((unsigned)s << 16);
}

__device__ __forceinline__ float wave_reduce_sum(float v) {
  #pragma unroll
  for (int off = 32; off; off >>= 1) v += __shfl_xor(v, off);
  return v;
}
__device__ __forceinline__ float wave_reduce_max(float v) {
  #pragma unroll
  for (int off = 32; off; off >>= 1) v = fmaxf(v, __shfl_xor(v, off));
  return v;
}

// ---------------------------------------------------------------------------
// Folded BN-stats, vectorized + fully unrolled (R15-proven).
// partial = [NBLK][16] f32 (cols 0..7 sums, 8..15 ssqs) read as float4.
// ---------------------------------------------------------------------------
template <int NBLK>
__device__ __forceinline__ void stats8v(const float4* __restrict__ part4,
                                        const float* __restrict__ g,
                                        const float* __restrict__ beta,
                                        float* __restrict__ A,
                                        float* __restrict__ Bc) {
  __shared__ float red[4][16];
  __shared__ float sums[16];
  const int tid = threadIdx.x;
  constexpr int K = (NBLK * 4) / 256;
  float ax = 0.f, ay = 0.f, az = 0.f, aw = 0.f;
  #pragma unroll
  for (int k = 0; k < K; ++k) {
    const float4 q = part4[tid + k * 256];
    ax += q.x; ay += q.y; az += q.z; aw += q.w;
  }
  #pragma unroll
  for (int off = 4; off <= 32; off <<= 1) {
    ax += __shfl_xor(ax, off);
    ay += __shfl_xor(ay, off);
    az += __shfl_xor(az, off);
    aw += __shfl_xor(aw, off);
  }
  const int lane = tid & 63, wv = tid >> 6;
  if (lane < 4) {
    red[wv][lane * 4 + 0] = ax;
    red[wv][lane * 4 + 1] = ay;
    red[wv][lane * 4 + 2] = az;
    red[wv][lane * 4 + 3] = aw;
  }
  __syncthreads();
  if (tid < 16)
    sums[tid] = red[0][tid] + red[1][tid] + red[2][tid] + red[3][tid];
  __syncthreads();
  if (tid < 8) {
    const float s = sums[tid], ss = sums[tid + 8];
    const float count = (float)NS_;
    const float mu = s / count;
    const float var = fmaxf(ss / count - mu * mu, 0.f);
    const float Av = g[tid] * rsqrtf(var + 1e-5f);
    red[0][tid] = Av;
    red[1][tid] = beta[tid] - mu * Av;
  }
  __syncthreads();
  #pragma unroll
  for (int i = 0; i < 8; ++i) { A[i] = red[0][i]; Bc[i] = red[1][i]; }
}

// BN+relu one 16B unit (8 channels of one e), repack to bf16 via cvt_pk
__device__ __forceinline__ uint4 bn_unit(uint4 v, const float* A, const float* B) {
  U8 in; in.u4 = v;
  unsigned ow[4];
  #pragma unroll
  for (int w = 0; w < 4; ++w) {
    const unsigned wd = in.u32[w];
    const float yl = fmaxf(0.f, fmaf(A[2 * w], bflo(wd), B[2 * w]));
    const float yh = fmaxf(0.f, fmaf(A[2 * w + 1], bfhi(wd), B[2 * w + 1]));
    ow[w] = cvt_pk_bf16(yl, yh);
  }
  return make_uint4(ow[0], ow[1], ow[2], ow[3]);
}

// ---------------------------------------------------------------------------
// init: PER-BLOCK max of i^2+q^2 (float4, no atomics).
// ---------------------------------------------------------------------------
__global__ __launch_bounds__(256) void k_init(const float4* __restrict__ id4,
                                              const float4* __restrict__ qd4,
                                              float* __restrict__ pmaxsq) {
  const int idx = blockIdx.x * 256 + threadIdx.x;
  const float4 iv = id4[idx];
  const float4 qv = qd4[idx];
  float m = fmaxf(fmaxf(iv.x * iv.x + qv.x * qv.x, iv.y * iv.y + qv.y * qv.y),
                  fmaxf(iv.z * iv.z + qv.z * qv.z, iv.w * iv.w + qv.w * qv.w));
  m = wave_reduce_max(m);
  __shared__ float sm[4];
  if ((threadIdx.x & 63) == 0) sm[threadIdx.x >> 6] = m;
  __syncthreads();
  if (threadIdx.x == 0)
    pmaxsq[blockIdx.x] = fmaxf(fmaxf(sm[0], sm[1]), fmaxf(sm[2], sm[3]));
}

// ---------------------------------------------------------------------------
// beamform, e-major output x0t[e][p]: coalesced 4B/lane stores.
// ---------------------------------------------------------------------------
__global__ __launch_bounds__(256) void k_beamform(
    const float4* __restrict__ id4, const float4* __restrict__ qd4,
    const float* __restrict__ angles, const float* __restrict__ ele_pos,
    const float* __restrict__ time_zero, const float* __restrict__ grid,
    const float4* __restrict__ pmaxsq4, unsigned* __restrict__ x0t) {
  __shared__ float2 sig[NSAMP];          // 16 KB
  __shared__ float smax[4];
  const int e = blockIdx.x & 127;
  const int chunk = blockIdx.x >> 7;     // 0..31

  const float4* irow = id4 + e * (NSAMP / 4);
  const float4* qrow = qd4 + e * (NSAMP / 4);
  #pragma unroll
  for (int k0 = 0; k0 < 2; ++k0) {
    const int k = k0 * 256 + threadIdx.x;
    const float4 iv = irow[k];
    const float4 qv = qrow[k];
    sig[4 * k + 0] = make_float2(iv.x, qv.x);
    sig[4 * k + 1] = make_float2(iv.y, qv.y);
    sig[4 * k + 2] = make_float2(iv.z, qv.z);
    sig[4 * k + 3] = make_float2(iv.w, qv.w);
  }
  // self-reduce the normalization max (16 KB, L2-hot; float4, unrolled)
  float mx = 0.f;
  #pragma unroll
  for (int k = 0; k < 4; ++k) {
    const float4 q = pmaxsq4[threadIdx.x + k * 256];
    mx = fmaxf(mx, fmaxf(fmaxf(q.x, q.y), fmaxf(q.z, q.w)));
  }
  mx = wave_reduce_max(mx);
  if ((threadIdx.x & 63) == 0) smax[threadIdx.x >> 6] = mx;
  __syncthreads();
  const float inv =
      1.0f / sqrtf(fmaxf(fmaxf(smax[0], smax[1]), fmaxf(smax[2], smax[3])));

  const float ang = angles[0];
  const float tz  = time_zero[0];

  constexpr float SC    = (float)(FS_D / C_D);
  constexpr float TH2R  = (float)(2.0 * FDEMOD_D / C_D);
  constexpr float TWOPI = (float)(2.0 * PI_D);

  const float sa = __sinf(ang);
  const float ca = __cosf(ang);
  const float ta = sa / ca;
  const float ex  = ele_pos[e * 3];
  const float ex0 = ele_pos[0];
  const float exl = ele_pos[127 * 3];

  #pragma unroll
  for (int s = 0; s < 4; ++s) {
    const int p = chunk * 1024 + s * 256 + threadIdx.x;
    const float px = grid[p * 3 + 0];
    const float pz = grid[p * 3 + 2];

    const float txdel = (px * sa + pz * ca + tz * (float)C_D) * SC;
    const float dx = px - ex;
    const float rxdel = sqrtf(dx * dx + pz * pz) * SC;

    const float delays = txdel + rxdel;
    const float d0 = floorf(delays);
    const float frac = delays - d0;
    const int i0 = (int)d0;

    const int c0 = min(max(i0, 0), NSAMP - 1);
    const int c1 = min(max(i0 + 1, 0), NSAMP - 1);
    const float2 s0 = sig[c0];
    const float2 s1 = sig[c1];
    const bool m0 = (i0 >= 0) && (i0 < NSAMP);
    const bool m1 = (i0 + 1 >= 0) && (i0 + 1 < NSAMP);
    const float iv0 = m0 ? s0.x : 0.f;
    const float qv0 = m0 ? s0.y : 0.f;
    const float iv1 = m1 ? s1.x : 0.f;
    const float qv1 = m1 ? s1.y : 0.f;
    const float ifoc = (iv0 * (1.f - frac) + iv1 * frac) * inv;
    const float qfoc = (qv0 * (1.f - frac) + qv1 * frac) * inv;

    // theta/2pi = delays*0.25 - pz*TH2R  (exact: FS = 4*FDEMOD)
    const float trev = fmaf(delays, 0.25f, -pz * TH2R);
    const float fr = trev - floorf(trev);
    const float st = __sinf(fr * TWOPI);
    const float ct = __cosf(fr * TWOPI);
    const float ir = ifoc * ct - qfoc * st;
    const float qr = qfoc * ct + ifoc * st;

    const float avx = fabsf(dx);
    const bool mrx = (fabsf(pz) > avx) || (avx <= 0.001f) ||
                     ((dx >= 0.001f) && (px <= ex0)) ||
                     ((dx <= -0.001f) && (px >= exl));
    const float xproj = px - pz * ta;
    const bool mtx = (xproj >= ex0 * 1.2f) && (xproj <= exl * 1.2f);
    const float a = (mrx && mtx) ? 1.f : 0.f;

    x0t[(size_t)e * NPIX + p] = cvt_pk_bf16(ir * a, qr * a);
  }
}

// ---------------------------------------------------------------------------
// conv1: IC=2, K=65, pad=32, OC=8.  Block-tiled LDS staging, PAIR-PACKED
// MFMA (rows 0..7 tile t, rows 8..15 tile t+1): 24 MFMA/px, full-wave
// epilogue.  Output: compact [p][128][8ch].
// ---------------------------------------------------------------------------
#define CONV1_P 32
#define ROWW    213

__global__ __launch_bounds__(256, 4) void k_conv1(
    const unsigned* __restrict__ x0t, const float* __restrict__ wgt,
    const float* __restrict__ bias, uint2* __restrict__ outp,
    float* __restrict__ partial,
    float* __restrict__ sumI, float* __restrict__ sumQ) {
  __shared__ unsigned tile[CONV1_P * ROWW];   // 27,264 B
  const int tid = threadIdx.x;
  const int lane = tid & 63;
  const int wv = tid >> 6;
  const int n = lane & 15, kq = lane >> 4;
  const int p0 = blockIdx.x * CONV1_P;

  // Pair-packed weight fragments: rows n<8 use window m (tile t); rows
  // n in 8..15 use window m-1 (tile t+1).  m=5/lower and m=0/upper are zero.
  short8 af2[6];
  #pragma unroll
  for (int m = 0; m < 6; ++m) {
    U8 u;
    #pragma unroll
    for (int j = 0; j < 8; ++j) {
      const int oc = n & 7;
      const int mm = (n < 8) ? m : (m - 1);
      const int tap = mm * 16 + kq * 4 + (j >> 1);
      const int ic = j & 1;
      const float w = (mm >= 0 && tap < 65) ? wgt[(oc * 2 + ic) * 65 + tap] : 0.f;
      u.us[j] = f2bf(w);
    }
    af2[m] = u.s8;
  }
  float bias_r[4];
  #pragma unroll
  for (int r = 0; r < 4; ++r) bias_r[r] = bias[(kq & 1) * 4 + r];

  // ---- stage tile: zero halos, transpose-load data [e][p] -> [p][32+e] ----
  for (int i = tid; i < CONV1_P * 32; i += 256)
    tile[(i >> 5) * ROWW + (i & 31)] = 0u;               // words [0,32)
  for (int i = tid; i < CONV1_P * 64; i += 256) {
    const int c = i & 63;
    if (c < ROWW - 160) tile[(i >> 6) * ROWW + 160 + c] = 0u;  // words [160,213)
  }
  {
    const int lp = tid & 31;
    const int e0 = tid >> 5;                              // 0..7
    #pragma unroll
    for (int i = 0; i < 16; ++i) {
      const int e = i * 8 + e0;
      tile[lp * ROWW + 32 + e] = x0t[(size_t)e * NPIX + p0 + lp];
    }
  }
  __syncthreads();

  float sum[4] = {0, 0, 0, 0}, ssq[4] = {0, 0, 0, 0};
  const int sbase = n + kq * 4;

  for (int j8 = 0; j8 < 8; ++j8) {
    const int lpx = wv * 8 + j8;
    const int p = p0 + lpx;
    const unsigned* row = tile + lpx * ROWW;
    uint2* orow = outp + (size_t)p * 256;

    // e-sums for k_final (bf16 inputs, same order as R10)
    {
      const unsigned v0 = row[32 + lane];
      const unsigned v1 = row[96 + lane];
      float si = bflo(v0) + bflo(v1);
      float sq = bfhi(v0) + bfhi(v1);
      si = wave_reduce_sum(si);
      sq = wave_reduce_sum(sq);
      if (lane == 0) { sumI[p] = si; sumQ[p] = sq; }
    }

    U8 win[12];
    #pragma unroll
    for (int q = 0; q < 12; ++q)
      #pragma unroll
      for (int c = 0; c < 4; ++c) win[q].u32[c] = row[sbase + 16 * q + c];

    #pragma unroll
    for (int pi = 0; pi < 4; ++pi) {
      f32x4 acc = {bias_r[0], bias_r[1], bias_r[2], bias_r[3]};
      #pragma unroll
      for (int m = 0; m < 6; ++m)
        acc = __builtin_amdgcn_mfma_f32_16x16x32_bf16(af2[m], win[2 * pi + m].s8,
                                                      acc, 0, 0, 0);
      // rows kq*4+r: kq<2 -> tile 2pi (oc=(kq&1)*4+r), kq>=2 -> tile 2pi+1
      const unsigned lo = cvt_pk_bf16(acc[0], acc[1]);
      const unsigned hi = cvt_pk_bf16(acc[2], acc[3]);
      orow[((2 * pi + (kq >> 1)) * 16 + n) * 2 + (kq & 1)] = make_uint2(lo, hi);
      #pragma unroll
      for (int r = 0; r < 4; ++r) { const float v = acc[r]; sum[r] += v; ssq[r] += v * v; }
    }
  }

  // reduce over n (offs 1..8), then combine kq<->kq+2 (off 32)
  #pragma unroll
  for (int off = 1; off <= 8; off <<= 1)
    #pragma unroll
    for (int r = 0; r < 4; ++r) { sum[r] += __shfl_xor(sum[r], off); ssq[r] += __shfl_xor(ssq[r], off); }
  #pragma unroll
  for (int r = 0; r < 4; ++r) { sum[r] += __shfl_xor(sum[r], 32); ssq[r] += __shfl_xor(ssq[r], 32); }
  __shared__ float s_red[4][16];
  if (lane == 0)
    #pragma unroll
    for (int r = 0; r < 4; ++r) { s_red[wv][r] = sum[r]; s_red[wv][8 + r] = ssq[r]; }
  if (lane == 16)
    #pragma unroll
    for (int r = 0; r < 4; ++r) { s_red[wv][4 + r] = sum[r]; s_red[wv][12 + r] = ssq[r]; }
  __syncthreads();
  if (tid < 16)
    partial[blockIdx.x * 16 + tid] =
        s_red[0][tid] + s_red[1][tid] + s_red[2][tid] + s_red[3][tid];
}

// ---------------------------------------------------------------------------
// conv2/3: IC=8, K=15, pad=7, OC=8.  Per-wave PRIVATE LDS row staging (no
// intra-loop barriers).  Input BN finalized in-kernel from predecessor's
// partial (stats8v<NBLK>, unrolled); BN+relu once per element; halos zeroed.
// SW-pipelined: next pixel's global loads issued before the MFMA tile loop.
// (R19 form, 52 VGPR — R17 dbuf and R20 pair-pack were null/regression.)
// ---------------------------------------------------------------------------
template <int NBLK_IN>
__global__ __launch_bounds__(256) void k_conv23(
    const uint4* __restrict__ inp, const float* __restrict__ wgt,
    const float* __restrict__ bias,
    const float4* __restrict__ part_in,
    const float* __restrict__ g_in, const float* __restrict__ be_in,
    uint2* __restrict__ outp, float* __restrict__ partial) {
  __shared__ uint4 s_row[4][144];
  const int tid = threadIdx.x;
  const int lane = tid & 63;
  const int wv = tid >> 6;
  const int gw = blockIdx.x * 4 + wv;
  const int n = lane & 15, kq = lane >> 4;

  // prologue load for first pixel (in flight across the stats fold)
  uint4 v0 = inp[(size_t)gw * 128 + lane];
  uint4 v1 = inp[(size_t)gw * 128 + 64 + lane];

  float A[8], Bc[8];
  stats8v<NBLK_IN>(part_in, g_in, be_in, A, Bc);

  short8 af[4];
  #pragma unroll
  for (int m = 0; m < 4; ++m) {
    U8 u;
    #pragma unroll
    for (int j = 0; j < 8; ++j) {
      const int tap = m * 4 + kq;
      const float w = (n < 8 && tap < 15) ? wgt[(n * 8 + j) * 15 + tap] : 0.f;
      u.us[j] = f2bf(w);
    }
    af[m] = u.s8;
  }
  float bias_r[4];
  #pragma unroll
  for (int r = 0; r < 4; ++r) {
    const int oo = kq * 4 + r;
    bias_r[r] = (oo < 8) ? bias[oo] : 0.f;
  }

  uint4* lds = s_row[wv];
  if (lane < 7)  lds[lane] = make_uint4(0, 0, 0, 0);
  if (lane >= 7 && lane < 16) lds[128 + lane] = make_uint4(0, 0, 0, 0);

  float sum[4] = {0, 0, 0, 0}, ssq[4] = {0, 0, 0, 0};

  #pragma unroll 1
  for (int it = 0; it < 4; ++it) {
    const int p = gw + it * 8192;
    lds[7 + lane]  = bn_unit(v0, A, Bc);
    lds[71 + lane] = bn_unit(v1, A, Bc);

    // prefetch next pixel (latency hides under the 32-MFMA tile loop)
    if (it < 3) {
      const uint4* ng = inp + (size_t)(p + 8192) * 128;
      v0 = ng[lane];
      v1 = ng[64 + lane];
    }

    uint2* orow = outp + (size_t)p * 256;
    for (int t = 0; t < 8; ++t) {
      f32x4 acc = {bias_r[0], bias_r[1], bias_r[2], bias_r[3]};
      const int base = t * 16 + n + kq;
      #pragma unroll
      for (int m = 0; m < 4; ++m) {
        U8 b;
        b.u4 = lds[base + m * 4];
        acc = __builtin_amdgcn_mfma_f32_16x16x32_bf16(af[m], b.s8, acc, 0, 0, 0);
      }
      if (lane < 32) {
        const unsigned lo = cvt_pk_bf16(acc[0], acc[1]);
        const unsigned hi = cvt_pk_bf16(acc[2], acc[3]);
        orow[(t * 16 + n) * 2 + kq] = make_uint2(lo, hi);
        #pragma unroll
        for (int r = 0; r < 4; ++r) { const float v = acc[r]; sum[r] += v; ssq[r] += v * v; }
      }
    }
  }

  #pragma unroll
  for (int off = 1; off <= 8; off <<= 1)
    #pragma unroll
    for (int r = 0; r < 4; ++r) { sum[r] += __shfl_xor(sum[r], off); ssq[r] += __shfl_xor(ssq[r], off); }
  __shared__ float s_red[4][16];
  if (lane == 0)
    #pragma unroll
    for (int r = 0; r < 4; ++r) { s_red[wv][r] = sum[r]; s_red[wv][8 + r] = ssq[r]; }
  if (lane == 16)
    #pragma unroll
    for (int r = 0; r < 4; ++r) { s_red[wv][4 + r] = sum[r]; s_red[wv][12 + r] = ssq[r]; }
  __syncthreads();
  if (tid < 16)
    partial[blockIdx.x * 16 + tid] =
        s_red[0][tid] + s_red[1][tid] + s_red[2][tid] + s_red[3][tid];
}

// ---------------------------------------------------------------------------
// conv4: IC=8, K=3, pad=1, OC=1.  VALU; BN3+relu fused on load (BN3 finalized
// in-kernel via stats8v<2048>); 1024 blocks x 16 outputs/thread (fold
// aggregate halved vs 2048 blocks).  Output bf16; partial = [1024][2].
// ---------------------------------------------------------------------------
__global__ __launch_bounds__(256) void k_conv4(
    const uint4* __restrict__ inp,
    const float4* __restrict__ part_in,
    const float* __restrict__ g3, const float* __restrict__ be3,
    const float* __restrict__ w4, const float* __restrict__ b4,
    unsigned short* __restrict__ y4b, float* __restrict__ partial) {
  float A[8], Bc[8];
  stats8v<2048>(part_in, g3, be3, A, Bc);

  const float bb = b4[0];
  float w4r[24];
  #pragma unroll
  for (int i = 0; i < 24; ++i) w4r[i] = w4[i];

  float s = 0.f, ss = 0.f;
  #pragma unroll 1
  for (int it = 0; it < 16; ++it) {
    const int idx = blockIdx.x * 256 + threadIdx.x + it * 262144;
    const int p = idx >> 7, e = idx & 127;
    float acc = bb;
    const uint4* row = inp + (size_t)p * 128 + e;
    #pragma unroll
    for (int kt = 0; kt < 3; ++kt) {
      const int ee = e + kt - 1;
      if (ee >= 0 && ee < E_) {
        U8 u; u.u4 = row[kt - 1];
        #pragma unroll
        for (int i = 0; i < 8; ++i) {
          const unsigned wd = u.u32[i >> 1];
          const float x = (i & 1) ? bfhi(wd) : bflo(wd);
          const float v = fmaxf(0.f, fmaf(A[i], x, Bc[i]));
          acc = fmaf(w4r[i * 3 + kt], v, acc);
        }
      }
    }
    y4b[idx] = f2bf(acc);
    s += acc;
    ss += acc * acc;
  }

  s = wave_reduce_sum(s);
  ss = wave_reduce_sum(ss);
  __shared__ float sm[4][2];
  if ((threadIdx.x & 63) == 0) { sm[threadIdx.x >> 6][0] = s; sm[threadIdx.x >> 6][1] = ss; }
  __syncthreads();
  if (threadIdx.x == 0) {
    partial[blockIdx.x * 2 + 0] = sm[0][0] + sm[1][0] + sm[2][0] + sm[3][0];
    partial[blockIdx.x * 2 + 1] = sm[0][1] + sm[1][1] + sm[2][1] + sm[3][1];
  }
}

// ---------------------------------------------------------------------------
// final: BN4 finalized in-kernel from conv4's 8KB partial (512 float4,
// 2 loads/thread); 2048 blocks x 16 pixels (4/wave).  singleW =
// sum_e relu(A4*y4+B4); comp = singleW*(sum_e x)/E; dB.  Per-block max
// over 16 pixels -> pmax[2048].
// ---------------------------------------------------------------------------
__global__ __launch_bounds__(256) void k_final(const float* __restrict__ sumI,
                                               const float* __restrict__ sumQ,
                                               const unsigned short* __restrict__ y4b,
                                               const float4* __restrict__ part_in,
                                               const float* __restrict__ g4,
                                               const float* __restrict__ be4,
                                               float* __restrict__ ydb,
                                               float* __restrict__ pmax) {
  __shared__ float sAB[2];
  {
    const int tid = threadIdx.x;
    // part_in = 1024 float2 pairs = 512 float4; 2 unrolled loads/thread
    float s = 0.f, ss = 0.f;
    #pragma unroll
    for (int k = 0; k < 2; ++k) {
      const float4 q = part_in[tid + k * 256];
      s += q.x + q.z;
      ss += q.y + q.w;
    }
    s = wave_reduce_sum(s);
    ss = wave_reduce_sum(ss);
    __shared__ float sm[4][2];
    if ((tid & 63) == 0) { sm[tid >> 6][0] = s; sm[tid >> 6][1] = ss; }
    __syncthreads();
    if (tid == 0) {
      s  = sm[0][0] + sm[1][0] + sm[2][0] + sm[3][0];
      ss = sm[0][1] + sm[1][1] + sm[2][1] + sm[3][1];
      const float count = (float)NS_;
      const float mu = s / count;
      const float var = fmaxf(ss / count - mu * mu, 0.f);
      const float Av = g4[0] * rsqrtf(var + 1e-5f);
      sAB[0] = Av;
      sAB[1] = be4[0] - mu * Av;
    }
    __syncthreads();
  }
  const float A = sAB[0], B = sAB[1];

  const int w = threadIdx.x >> 6;
  const int lane = threadIdx.x & 63;
  __shared__ float s_m[4][4];

  #pragma unroll
  for (int j = 0; j < 4; ++j) {
    const int p = blockIdx.x * 16 + w * 4 + j;
    const size_t base = (size_t)p * E_;
    float sw = fmaxf(0.f, fmaf(A, bf2f(y4b[base + lane]), B)) +
               fmaxf(0.f, fmaf(A, bf2f(y4b[base + lane + 64]), B));
    sw = wave_reduce_sum(sw);
    if (lane == 0) {
      const float ci = sw * sumI[p] * (1.f / (float)E_);
      const float cq = sw * sumQ[p] * (1.f / (float)E_);
      const float mag = sqrtf(ci * ci + cq * cq);
      const float v = 20.f * log10f(mag + 1e-20f);
      ydb[p] = v;
      s_m[w][j] = v;
    }
  }
  __syncthreads();
  if (threadIdx.x == 0) {
    float m = -3.4e38f;
    #pragma unroll
    for (int w2 = 0; w2 < 4; ++w2)
      #pragma unroll
      for (int j = 0; j < 4; ++j) m = fmaxf(m, s_m[w2][j]);
    pmax[blockIdx.x] = m;
  }
}

// k_sub with inline global-max: each block re-reduces pmax[2048] (float4)
__global__ __launch_bounds__(256) void k_sub(const float* __restrict__ ydb,
                                             const float4* __restrict__ pmax4,
                                             float* __restrict__ out) {
  float m = -3.4e38f;
  #pragma unroll
  for (int k = 0; k < 2; ++k) {
    const float4 q = pmax4[threadIdx.x + k * 256];
    m = fmaxf(m, fmaxf(fmaxf(q.x, q.y), fmaxf(q.z, q.w)));
  }
  m = wave_reduce_max(m);
  __shared__ float sm[4];
  if ((threadIdx.x & 63) == 0) sm[threadIdx.x >> 6] = m;
  __syncthreads();
  __shared__ float sgm;
  if (threadIdx.x == 0)
    sgm = fmaxf(fmaxf(sm[0], sm[1]), fmaxf(sm[2], sm[3]));
  __syncthreads();
  const int i = blockIdx.x * 256 + threadIdx.x;
  out[i] = ydb[i] - sgm;
}

// ---------------------------------------------------------------------------
// Workspace layout (bytes).  Region A is time-multiplexed:
//   x0t (16.7MB) -> buf2 (67MB, dead after conv3) -> y4b (8.4MB) + ydb + pmax.
// partial is double-buffered: part0/part1 (128KB each).
// ---------------------------------------------------------------------------
static constexpr size_t OFF_A     = 0;            // 67,108,864 region
static constexpr size_t OFF_Y4    = 0;            // bf16 [NS]  (in A)
static constexpr size_t OFF_YDB   = 16777216;     // f32 [NPIX] (in A)
static constexpr size_t OFF_PMAX  = 16908288;     // f32 [2048] (in A)
static constexpr size_t OFF_BUF1  = 67108864;     // 67,108,864
static constexpr size_t OFF_SUMI  = 134217728;    // 131,072
static constexpr size_t OFF_SUMQ  = 134348800;    // 131,072
static constexpr size_t OFF_PART0 = 134479872;    // 131,072
static constexpr size_t OFF_PART1 = 134610944;    // 131,072
static constexpr size_t OFF_PMSQ  = 134742016;    // 16,384 (4096 f32)

extern "C" void kernel_launch(void* const* d_in, const int* in_sizes, int n_in,
                              void* d_out, int out_size, void* d_ws, size_t ws_size,
                              hipStream_t stream) {
  const float* idata     = (const float*)d_in[0];
  const float* qdata     = (const float*)d_in[1];
  const float* angles    = (const float*)d_in[2];
  const float* ele_pos   = (const float*)d_in[3];
  const float* time_zero = (const float*)d_in[4];
  const float* grid      = (const float*)d_in[5];
  const float* w1 = (const float*)d_in[6];  const float* b1 = (const float*)d_in[7];
  const float* g1 = (const float*)d_in[8];  const float* be1 = (const float*)d_in[9];
  const float* w2 = (const float*)d_in[10]; const float* b2 = (const float*)d_in[11];
  const float* g2 = (const float*)d_in[12]; const float* be2 = (const float*)d_in[13];
  const float* w3 = (const float*)d_in[14]; const float* b3 = (const float*)d_in[15];
  const float* g3 = (const float*)d_in[16]; const float* be3 = (const float*)d_in[17];
  const float* w4 = (const float*)d_in[18]; const float* b4 = (const float*)d_in[19];
  const float* g4 = (const float*)d_in[20]; const float* be4 = (const float*)d_in[21];

  char* ws = (char*)d_ws;
  unsigned*       x0t   = (unsigned*)(ws + OFF_A);       // [e][p] bf16-pairs
  uint4*          buf2  = (uint4*)(ws + OFF_A);          // [p][128] units
  unsigned short* y4b   = (unsigned short*)(ws + OFF_Y4);
  float*          ydb   = (float*)(ws + OFF_YDB);
  float*          pmax  = (float*)(ws + OFF_PMAX);
  uint4*          buf1  = (uint4*)(ws + OFF_BUF1);
  float*          sumI  = (float*)(ws + OFF_SUMI);
  float*          sumQ  = (float*)(ws + OFF_SUMQ);
  float*          part0 = (float*)(ws + OFF_PART0);
  float*          part1 = (float*)(ws + OFF_PART1);
  float*          pmsq  = (float*)(ws + OFF_PMSQ);

  k_init<<<4096, 256, 0, stream>>>((const float4*)idata, (const float4*)qdata, pmsq);
  k_beamform<<<4096, 256, 0, stream>>>((const float4*)idata, (const float4*)qdata,
                                       angles, ele_pos, time_zero, grid,
                                       (const float4*)pmsq, x0t);

  k_conv1<<<NPIX / CONV1_P, 256, 0, stream>>>(x0t, w1, b1, (uint2*)buf1, part0,
                                              sumI, sumQ);

  k_conv23<1024><<<2048, 256, 0, stream>>>(buf1, w2, b2, (const float4*)part0,
                                           g1, be1, (uint2*)buf2, part1);

  k_conv23<2048><<<2048, 256, 0, stream>>>(buf2, w3, b3, (const float4*)part1,
                                           g2, be2, (uint2*)buf1, part0);

  k_conv4<<<1024, 256, 0, stream>>>(buf1, (const float4*)part0, g3, be3,
                                    w4, b4, y4b, part1);

  k_final<<<2048, 256, 0, stream>>>(sumI, sumQ, y4b, (const float4*)part1,
                                    g4, be4, ydb, pmax);
  k_sub<<<NPIX / 256, 256, 0, stream>>>(ydb, (const float4*)pmax, (float*)d_out);
}